// Round 9
// baseline (534.255 us; speedup 1.0000x reference)
//
#include <hip/hip_runtime.h>

#define NCLS 19
#define HWSZ (512*1024)
#define NB   8
#define CHUNK 2048            // pixels per block
#define TPX   64              // pixels per tile
#define NT    (CHUNK/TPX)     // 32 tiles
#define EPSM  1e-6f
#define EPSPD 1e-6f

#define ROWP 20
#define COLP 32
#define SUMS_ELEMS (NB*2*ROWP*COLP)

#define REGION 160            // float4 slots per wave region (152 data + 8 count)
#define DHALF  640            // 4 waves * REGION per dbuf half

typedef short bf16x8 __attribute__((ext_vector_type(8)));
typedef float f32x16 __attribute__((ext_vector_type(16)));
typedef unsigned uint4v __attribute__((ext_vector_type(4)));

// fp32 -> packed bf16 hi / lo (exact split; hi = truncation, lo = remainder)
#define CVT(pA, pB, HI, LO) {                                                      \
    const unsigned uA = __builtin_bit_cast(unsigned, pA);                          \
    const unsigned uB = __builtin_bit_cast(unsigned, pB);                          \
    HI = __builtin_amdgcn_perm(uB, uA, 0x07060302u);                               \
    const float fa = (pA) - __builtin_bit_cast(float, uA & 0xFFFF0000u);           \
    const float fb = (pB) - __builtin_bit_cast(float, uB & 0xFFFF0000u);           \
    LO = __builtin_amdgcn_perm(__builtin_bit_cast(unsigned, fb),                   \
                               __builtin_bit_cast(unsigned, fa), 0x07060302u); }

#define BBIT(word, sh, ei) { const unsigned lb_ = ((word) >> (sh)) & 255u;         \
    B[ei] = (lb_ == ur) ? (short)0x3F80 : (short)0; }

// per-lane staging descriptor j: f = j*64+lane -> (row, granule g) of wave's half
#define SGI(j) { const int f_ = (j)*64 + lane;                                     \
    const int row_ = f_ >> 3, g_ = f_ & 7;                                         \
    const int lb_ = ((g_ >> 2) << 1) | (g_ & 1);                                   \
    const int kg_ = (g_ >> 1) & 1;                                                 \
    lidx##j = lb_*40 + ((kg_*20 + row_) ^ lb_);                                    \
    gp##j = X + ((long)(n*NCLS + (row_ < NCLS ? row_ : 0)))*HWSZ                   \
              + chunk0 + ph*32 + g_*4; }

#define LOADS(set, tt) {                                                           \
    x##set##0 = *(const float4*)(gp0 + (tt)*TPX);                                  \
    x##set##1 = *(const float4*)(gp1 + (tt)*TPX);                                  \
    if (lane < 24) x##set##2 = *(const float4*)(gp2 + (tt)*TPX); }

#define WRITES(set, rg) {                                                          \
    (rg)[lidx0] = x##set##0;                                                       \
    (rg)[lidx1] = x##set##1;                                                       \
    if (lane < 24) (rg)[lidx2] = x##set##2; }

// fragment read-ahead: labels + 4 swizzled slots for 2 K-steps
#define FR_DECL(s) float4 fd##s##0, fd##s##1, fd##s##2, fd##s##3;                  \
                   uint2 fp##s##0, fp##s##1;

#define DSREAD(s, rg, t_) {                                                        \
    fp##s##0 = *(const uint2*)(labP + (t_)*TPX);                                   \
    fp##s##1 = *(const uint2*)(labP + (t_)*TPX + 16);                              \
    fd##s##0 = (rg)[idx00]; fd##s##1 = (rg)[idx01];                                \
    fd##s##2 = (rg)[idx10]; fd##s##3 = (rg)[idx11]; }

#define KSTEP2(pk, d0, d1) {                                                       \
    bf16x8 B;                                                                      \
    BBIT(pk.x, 0, 0) BBIT(pk.x, 8, 1) BBIT(pk.x, 16, 2) BBIT(pk.x, 24, 3)         \
    BBIT(pk.y, 0, 4) BBIT(pk.y, 8, 5) BBIT(pk.y, 16, 6) BBIT(pk.y, 24, 7)         \
    unsigned h0, h1, h2, h3, l0_, l1_, l2_, l3_;                                   \
    CVT(d0.x, d0.y, h0, l0_)  CVT(d0.z, d0.w, h1, l1_)                             \
    CVT(d1.x, d1.y, h2, l2_)  CVT(d1.z, d1.w, h3, l3_)                             \
    const bf16x8 hi = __builtin_bit_cast(bf16x8, (uint4v){h0, h1, h2, h3});        \
    const bf16x8 lo = __builtin_bit_cast(bf16x8, (uint4v){l0_, l1_, l2_, l3_});    \
    acc = __builtin_amdgcn_mfma_f32_32x32x16_bf16(hi, B, acc, 0, 0, 0);            \
    acc = __builtin_amdgcn_mfma_f32_32x32x16_bf16(lo, B, acc, 0, 0, 0); }

#define COMPUTE2(s) { KSTEP2(fp##s##0, fd##s##0, fd##s##1)                         \
                      KSTEP2(fp##s##1, fd##s##2, fd##s##3) }

__global__ __launch_bounds__(256, 4) void icl_sums(
    const float* __restrict__ S, const float* __restrict__ T,
    const int* __restrict__ gt, float* __restrict__ sums)
{
    __shared__ float4 buf4[2*DHALF];           // 20.5 KB: [dbuf][wave][160]
    __shared__ unsigned char labU[CHUNK];      // 2 KB
    __shared__ float red[2][ROWP][COLP];       // 5 KB

    const int tid = threadIdx.x;
    const int n   = blockIdx.y;
    const long chunk0 = (long)blockIdx.x * CHUNK;

    for (int i = tid; i < 2 * ROWP * COLP; i += 256) ((float*)red)[i] = 0.f;

    // labels -> packed u8 in LDS (coalesced, block-shared)
    {
        const int4* gp = (const int4*)(gt + (long)n * HWSZ + chunk0);
        const int4 a = gp[tid], b = gp[tid + 256];
        ((unsigned*)labU)[tid] = (unsigned)a.x | ((unsigned)a.y << 8) |
                                 ((unsigned)a.z << 16) | ((unsigned)a.w << 24);
        ((unsigned*)labU)[tid + 256] = (unsigned)b.x | ((unsigned)b.y << 8) |
                                       ((unsigned)b.z << 16) | ((unsigned)b.w << 24);
    }
    __syncthreads();   // labU + red visible; ONLY block-wide barrier until epilogue

    const int wave = tid >> 6, lane = tid & 63;
    const int r  = lane & 31;                   // A-row (channel) / B-col (class)
    const int kg = lane >> 5;                   // 8-px half of the 16-px K-step
    const bool isT = wave >= 2;                 // waves 0,1 -> S ; 2,3 -> T
    const int  ph  = wave & 1;                  // 32-px half of the 64-px tile
    const unsigned ur = (unsigned)r;

    const float* X = isT ? T : S;

    // staging descriptors (wave-private region, coalesced global source)
    int lidx0, lidx1, lidx2;
    const float *gp0, *gp1, *gp2;
    SGI(0) SGI(1) SGI(2)

    // wave-private dbuf regions
    float4* reg0 = buf4 + wave * REGION;
    float4* reg1 = buf4 + DHALF + wave * REGION;

    // prefill count slots (slot kg*20+19 of each blk) with 1.0 in both regions;
    // stagers only write rows 0..18, so these persist.
    if (lane < 16) {
        const int d_ = lane >> 3, rem = lane & 7, lb = rem >> 1, kg_ = rem & 1;
        buf4[d_*DHALF + wave*REGION + lb*40 + (((kg_*20) + 19) ^ lb)] =
            make_float4(1.f, 1.f, 1.f, 1.f);
    }

    // A-fragment read slots (region-local): blk = i*2+p, slot = kg*20+sr
    const int sr = (r < 20) ? r : r - 12;       // r>=20: harmless dup rows
    const int sl = kg * 20 + sr;
    const int idx00 = 0*40 + (sl ^ 0);
    const int idx01 = 1*40 + (sl ^ 1);
    const int idx10 = 2*40 + (sl ^ 2);
    const int idx11 = 3*40 + (sl ^ 3);

    const unsigned char* labP = labU + ph * 32 + kg * 8;

    f32x16 acc = {0,0,0,0,0,0,0,0,0,0,0,0,0,0,0,0};
    float4 xA0, xA1, xA2, xB0, xB1, xB2;
    FR_DECL(C) FR_DECL(N)

    // ---- pipeline prologue ----
    LOADS(A, 0) LOADS(B, 1)
    WRITES(A, reg0)            // tile 0
    LOADS(A, 2)
    DSREAD(C, reg0, 0)
    WRITES(B, reg1)            // tile 1
    LOADS(B, 3)
    DSREAD(N, reg1, 1)

    // ---- steady state: compute t while staging t+2 and loading t+4 ----
    for (int t = 0; t < NT - 4; t += 2) {
        COMPUTE2(C)            // tile t
        WRITES(A, reg0)        // tile t+2
        LOADS(A, t + 4)
        DSREAD(C, reg0, t + 2)
        COMPUTE2(N)            // tile t+1
        WRITES(B, reg1)        // tile t+3
        LOADS(B, t + 5)
        DSREAD(N, reg1, t + 3)
    }

    // ---- epilogue: tiles NT-4 .. NT-1, no more global loads ----
    COMPUTE2(C)                // NT-4
    WRITES(A, reg0)            // NT-2
    DSREAD(C, reg0, NT - 2)
    COMPUTE2(N)                // NT-3
    WRITES(B, reg1)            // NT-1
    DSREAD(N, reg1, NT - 1)
    COMPUTE2(C)                // NT-2
    COMPUTE2(N)                // NT-1

    // C/D layout: col = lane&31, row = (e&3) + 8*(e>>2) + 4*kg (row19 = counts)
#pragma unroll
    for (int e = 0; e < 16; ++e) {
        const int row = (e & 3) + 8 * (e >> 2) + 4 * kg;
        if (row < ROWP) atomicAdd(&red[isT ? 1 : 0][row][r], acc[e]);
    }
    __syncthreads();

    float* gs = sums + (long)n * 2 * ROWP * COLP;
    for (int i = tid; i < 2 * ROWP * COLP; i += 256) {
        if ((i & 31) < NCLS) atomicAdd(&gs[i], ((const float*)red)[i]);
    }
}

__global__ __launch_bounds__(256) void icl_final(
    const float* __restrict__ sums, float* __restrict__ out)
{
    __shared__ float v[NB][2][NCLS][NCLS];   // [n][t][k][c]
    __shared__ float red2[256];
    const int tid = threadIdx.x;

    for (int i = tid; i < NB * 2 * NCLS * NCLS; i += 256) {
        const int c = i % NCLS;
        const int k = (i / NCLS) % NCLS;
        const int t = (i / (NCLS * NCLS)) % 2;
        const int n = i / (2 * NCLS * NCLS);
        const float cnt = sums[((n * 2 + 0) * ROWP + NCLS) * COLP + k];
        const float val = sums[((n * 2 + t) * ROWP + c) * COLP + k];
        v[n][t][k][c] = val * (1.f / (cnt + EPSM));
    }
    __syncthreads();

    float acc = 0.f;
    const int NPAIR = NCLS * (NCLS - 1) / 2;   // 171
    for (int i = tid; i < NB * NPAIR; i += 256) {
        const int n = i / NPAIR;
        int rem = i % NPAIR;
        int k1 = 0;
        while (rem >= NCLS - 1 - k1) { rem -= NCLS - 1 - k1; ++k1; }
        const int k2 = k1 + 1 + rem;
        float ss = 0.f, st = 0.f;
#pragma unroll
        for (int c = 0; c < NCLS; ++c) {
            const float ds = v[n][0][k1][c] - v[n][0][k2][c] + EPSPD;
            const float dt = v[n][1][k1][c] - v[n][1][k2][c] + EPSPD;
            ss = fmaf(ds, ds, ss);
            st = fmaf(dt, dt, st);
        }
        const float e = sqrtf(st) - sqrtf(ss);
        acc += 0.5f * e * e;
    }

    red2[tid] = acc;
    __syncthreads();
    for (int s = 128; s > 0; s >>= 1) {
        if (tid < s) red2[tid] += red2[tid + s];
        __syncthreads();
    }
    if (tid == 0) out[0] = 0.5f * red2[0] / (float)NB;
}

extern "C" void kernel_launch(void* const* d_in, const int* in_sizes, int n_in,
                              void* d_out, int out_size, void* d_ws, size_t ws_size,
                              hipStream_t stream) {
    const float* S  = (const float*)d_in[0];
    const float* T  = (const float*)d_in[1];
    const int*   gt = (const int*)d_in[2];

    float* sums = (float*)d_ws;
    hipMemsetAsync(d_ws, 0, SUMS_ELEMS * sizeof(float), stream);

    dim3 grid(HWSZ / CHUNK, NB);   // (256, 8) = 2048 blocks
    icl_sums<<<grid, 256, 0, stream>>>(S, T, gt, sums);
    icl_final<<<1, 256, 0, stream>>>(sums, (float*)d_out);
}

// Round 10
// 155.483 us; speedup vs baseline: 3.4361x; 3.4361x over previous
//
#include <hip/hip_runtime.h>

#define NCLS 19
#define HWSZ (512*1024)
#define NB   8
#define CHUNK 2048            // pixels per block
#define TPX   64              // pixels per tile
#define NT    (CHUNK/TPX)     // 32 tiles
#define EPSM  1e-6f
#define EPSPD 1e-6f

#define ROWP 20
#define COLP 32
#define SUMS_ELEMS (NB*2*ROWP*COLP)
#define F4T  (NCLS*TPX/4)     // 304 float4 granules per tensor-tile

typedef short bf16x8 __attribute__((ext_vector_type(8)));
typedef float f32x16 __attribute__((ext_vector_type(16)));
typedef unsigned uint4v __attribute__((ext_vector_type(4)));

// fp32 -> packed bf16 hi / lo (exact split; hi = truncation, lo = remainder)
#define CVT(pA, pB, HI, LO) {                                                      \
    const unsigned uA = __builtin_bit_cast(unsigned, pA);                          \
    const unsigned uB = __builtin_bit_cast(unsigned, pB);                          \
    HI = __builtin_amdgcn_perm(uB, uA, 0x07060302u);                               \
    const float fa = (pA) - __builtin_bit_cast(float, uA & 0xFFFF0000u);           \
    const float fb = (pB) - __builtin_bit_cast(float, uB & 0xFFFF0000u);           \
    LO = __builtin_amdgcn_perm(__builtin_bit_cast(unsigned, fb),                   \
                               __builtin_bit_cast(unsigned, fa), 0x07060302u); }

#define BBIT(word, sh, ei) { const unsigned lb_ = ((word) >> (sh)) & 255u;         \
    B[ei] = (lb_ == ur) ? (short)0x3F80 : (short)0; }

// staging descriptor j: f = tid + j*256 -> (row, granule g); blk = st*2+q
#define SGI(j) { int f = tid + (j)*256;                                            \
    if (f >= F4T) f = F4T - 1;                                                     \
    const int row_ = f >> 4, g_ = f & 15;                                          \
    const int blk_ = ((g_ >> 2) << 1) | (g_ & 1);                                  \
    const int slot_ = (((g_ >> 1) & 1) * 20) + row_;                               \
    widx##j = blk_*40 + (slot_ ^ blk_);                                            \
    const long po_ = ((long)(n*NCLS + row_))*HWSZ + chunk0 + (g_ << 2);            \
    sp##j = S + po_;  tp##j = T + po_; }

#define SG_DECL(set) float4 s##set##0, s##set##1, t##set##0, t##set##1;

#define LOADS(set, tt) {                                                           \
    s##set##0 = *(const float4*)(sp0 + (long)(tt)*TPX);                            \
    t##set##0 = *(const float4*)(tp0 + (long)(tt)*TPX);                            \
    if (act1) {                                                                    \
        s##set##1 = *(const float4*)(sp1 + (long)(tt)*TPX);                        \
        t##set##1 = *(const float4*)(tp1 + (long)(tt)*TPX); } }

#define WRITES(set) {                                                              \
    buf4[widx0]       = s##set##0;                                                 \
    buf4[widx0 + 320] = t##set##0;                                                 \
    if (act1) {                                                                    \
        buf4[widx1]       = s##set##1;                                             \
        buf4[widx1 + 320] = t##set##1; } }

#define KSTEP2(pk, d0, d1) {                                                       \
    bf16x8 B;                                                                      \
    BBIT(pk.x, 0, 0) BBIT(pk.x, 8, 1) BBIT(pk.x, 16, 2) BBIT(pk.x, 24, 3)         \
    BBIT(pk.y, 0, 4) BBIT(pk.y, 8, 5) BBIT(pk.y, 16, 6) BBIT(pk.y, 24, 7)         \
    unsigned h0, h1, h2, h3, l0_, l1_, l2_, l3_;                                   \
    CVT(d0.x, d0.y, h0, l0_)  CVT(d0.z, d0.w, h1, l1_)                             \
    CVT(d1.x, d1.y, h2, l2_)  CVT(d1.z, d1.w, h3, l3_)                             \
    const bf16x8 hi = __builtin_bit_cast(bf16x8, (uint4v){h0, h1, h2, h3});        \
    const bf16x8 lo = __builtin_bit_cast(bf16x8, (uint4v){l0_, l1_, l2_, l3_});    \
    acc = __builtin_amdgcn_mfma_f32_32x32x16_bf16(hi, B, acc, 0, 0, 0);            \
    acc = __builtin_amdgcn_mfma_f32_32x32x16_bf16(lo, B, acc, 0, 0, 0); }

#define COMPUTE(t_) {                                                              \
    const uint2 pk0 = *(const uint2*)(labB + (t_)*TPX);                            \
    const uint2 pk1 = *(const uint2*)(labB + (t_)*TPX + 16);                       \
    const float4 a0 = xb4[i00], a1 = xb4[i01];                                     \
    const float4 b0 = xb4[i10], b1 = xb4[i11];                                     \
    KSTEP2(pk0, a0, a1)  KSTEP2(pk1, b0, b1) }

// raw barriers: never drain vmcnt (the in-flight prefetch survives the barrier);
// lgkmcnt(0) makes this wave's ds_writes visible before the barrier.
#define PHASE(set, t_) {                                                           \
    WRITES(set)                                                                    \
    if ((t_) + 4 < NT) { LOADS(set, (t_) + 4) }                                    \
    asm volatile("s_waitcnt lgkmcnt(0)" ::: "memory");                             \
    __builtin_amdgcn_s_barrier();                                                  \
    COMPUTE(t_)                                                                    \
    __builtin_amdgcn_s_barrier(); }

__global__ __launch_bounds__(256, 3) void icl_sums(
    const float* __restrict__ S, const float* __restrict__ T,
    const int* __restrict__ gt, float* __restrict__ sums)
{
    __shared__ float4 buf4[2*320];             // 10 KB: [S | T], 8 blk x 40 slots
    __shared__ unsigned char labU[CHUNK];      // 2 KB
    __shared__ float red[2][ROWP][COLP];       // 5 KB

    const int tid = threadIdx.x;
    const int n   = blockIdx.y;
    const long chunk0 = (long)blockIdx.x * CHUNK;

    for (int i = tid; i < 2 * ROWP * COLP; i += 256) ((float*)red)[i] = 0.f;

    // labels -> packed u8 in LDS (coalesced)
    {
        const int4* gp = (const int4*)(gt + (long)n * HWSZ + chunk0);
        const int4 a = gp[tid], b = gp[tid + 256];
        ((unsigned*)labU)[tid] = (unsigned)a.x | ((unsigned)a.y << 8) |
                                 ((unsigned)a.z << 16) | ((unsigned)a.w << 24);
        ((unsigned*)labU)[tid + 256] = (unsigned)b.x | ((unsigned)b.y << 8) |
                                       ((unsigned)b.z << 16) | ((unsigned)b.w << 24);
    }

    // prefill count slots (slot kg*20+19 of each blk, both tensors); stagers
    // only write rows 0..18, so these persist across all tiles.
    if (tid < 32) {
        const int blk = tid >> 2, kg_ = (tid >> 1) & 1, tb = tid & 1;
        buf4[tb*320 + blk*40 + (((kg_*20) + 19) ^ blk)] = make_float4(1.f,1.f,1.f,1.f);
    }

    const int wave = tid >> 6, lane = tid & 63;
    const int r  = lane & 31;                   // A-row (channel) / B-col (class)
    const int kg = lane >> 5;                   // 8-px half of the 16-px K-step
    const bool isT = wave >= 2;                 // waves 0,1 -> S ; 2,3 -> T
    const int  ph  = wave & 1;                  // 32-px half of the 64-px tile
    const unsigned ur = (unsigned)r;
    const bool act1 = (tid + 256) < F4T;        // j=1 staging active (tid < 48)

    int widx0, widx1;
    const float *sp0, *tp0, *sp1, *tp1;
    SGI(0) SGI(1)
    SG_DECL(A) SG_DECL(B) SG_DECL(C) SG_DECL(D)

    // A-fragment read slots: blk = ph*4 + i*2 + q, idx = blk*40 + (slot ^ blk)
    const int sr = (r < 20) ? r : r - 12;       // r>=20: harmless dup rows
    const int sl = kg * 20 + sr;
    const int i00 = (ph*4+0)*40 + (sl ^ (ph*4+0));
    const int i01 = (ph*4+1)*40 + (sl ^ (ph*4+1));
    const int i10 = (ph*4+2)*40 + (sl ^ (ph*4+2));
    const int i11 = (ph*4+3)*40 + (sl ^ (ph*4+3));

    const float4* xb4 = buf4 + (isT ? 320 : 0);
    const unsigned char* labB = labU + ph * 32 + kg * 8;

    f32x16 acc = {0,0,0,0,0,0,0,0,0,0,0,0,0,0,0,0};

    __syncthreads();   // labels + prefill + red visible; vmcnt baseline = 0

    LOADS(A, 0) LOADS(B, 1) LOADS(C, 2) LOADS(D, 3)

    for (int t = 0; t < NT; t += 4) {
        PHASE(A, t)
        PHASE(B, t + 1)
        PHASE(C, t + 2)
        PHASE(D, t + 3)
    }

    // C/D layout: col = lane&31, row = (e&3) + 8*(e>>2) + 4*kg (row19 = counts)
#pragma unroll
    for (int e = 0; e < 16; ++e) {
        const int row = (e & 3) + 8 * (e >> 2) + 4 * kg;
        if (row < ROWP) atomicAdd(&red[isT ? 1 : 0][row][r], acc[e]);
    }
    __syncthreads();

    float* gs = sums + (long)n * 2 * ROWP * COLP;
    for (int i = tid; i < 2 * ROWP * COLP; i += 256) {
        if ((i & 31) < NCLS) atomicAdd(&gs[i], ((const float*)red)[i]);
    }
}

__global__ __launch_bounds__(256) void icl_final(
    const float* __restrict__ sums, float* __restrict__ out)
{
    __shared__ float v[NB][2][NCLS][NCLS];   // [n][t][k][c]
    __shared__ float red2[256];
    const int tid = threadIdx.x;

    for (int i = tid; i < NB * 2 * NCLS * NCLS; i += 256) {
        const int c = i % NCLS;
        const int k = (i / NCLS) % NCLS;
        const int t = (i / (NCLS * NCLS)) % 2;
        const int n = i / (2 * NCLS * NCLS);
        const float cnt = sums[((n * 2 + 0) * ROWP + NCLS) * COLP + k];
        const float val = sums[((n * 2 + t) * ROWP + c) * COLP + k];
        v[n][t][k][c] = val * (1.f / (cnt + EPSM));
    }
    __syncthreads();

    float acc = 0.f;
    const int NPAIR = NCLS * (NCLS - 1) / 2;   // 171
    for (int i = tid; i < NB * NPAIR; i += 256) {
        const int n = i / NPAIR;
        int rem = i % NPAIR;
        int k1 = 0;
        while (rem >= NCLS - 1 - k1) { rem -= NCLS - 1 - k1; ++k1; }
        const int k2 = k1 + 1 + rem;
        float ss = 0.f, st = 0.f;
#pragma unroll
        for (int c = 0; c < NCLS; ++c) {
            const float ds = v[n][0][k1][c] - v[n][0][k2][c] + EPSPD;
            const float dt = v[n][1][k1][c] - v[n][1][k2][c] + EPSPD;
            ss = fmaf(ds, ds, ss);
            st = fmaf(dt, dt, st);
        }
        const float e = sqrtf(st) - sqrtf(ss);
        acc += 0.5f * e * e;
    }

    red2[tid] = acc;
    __syncthreads();
    for (int s = 128; s > 0; s >>= 1) {
        if (tid < s) red2[tid] += red2[tid + s];
        __syncthreads();
    }
    if (tid == 0) out[0] = 0.5f * red2[0] / (float)NB;
}

extern "C" void kernel_launch(void* const* d_in, const int* in_sizes, int n_in,
                              void* d_out, int out_size, void* d_ws, size_t ws_size,
                              hipStream_t stream) {
    const float* S  = (const float*)d_in[0];
    const float* T  = (const float*)d_in[1];
    const int*   gt = (const int*)d_in[2];

    float* sums = (float*)d_ws;
    hipMemsetAsync(d_ws, 0, SUMS_ELEMS * sizeof(float), stream);

    dim3 grid(HWSZ / CHUNK, NB);   // (256, 8) = 2048 blocks
    icl_sums<<<grid, 256, 0, stream>>>(S, T, gt, sums);
    icl_final<<<1, 256, 0, stream>>>(sums, (float*)d_out);
}